// Round 1
// baseline (424.883 us; speedup 1.0000x reference)
//
#include <hip/hip_runtime.h>
#include <hip/hip_bf16.h>
#include <cstddef>

#define NN 8192
#define FF 128
#define EPSF 1e-8f
#define KSPLIT 4

typedef __attribute__((ext_vector_type(8))) short short8_t;
typedef __attribute__((ext_vector_type(4))) float f32x4_t;

static __device__ __forceinline__ unsigned short f2bf(float f) {
    unsigned u = __builtin_bit_cast(unsigned, f);
    u = (u + 0x7FFFu + ((u >> 16) & 1u)) >> 16;   // round-to-nearest-even
    return (unsigned short)u;
}
static __device__ __forceinline__ float bf2f(unsigned short h) {
    return __builtin_bit_cast(float, ((unsigned)h) << 16);
}

// ---------------------------------------------------------------------------
// Pass 1: degree[i] = sum_j (adj + learn + eps*noise)[i][j] + 1 (self loop)
//         s[i] = (degree + eps)^-1/2
// One block per row; 768 MB streaming read.
// ---------------------------------------------------------------------------
__global__ __launch_bounds__(256) void degree_kernel(
    const float* __restrict__ adj, const float* __restrict__ learn,
    const float* __restrict__ noise, float* __restrict__ s_out)
{
    const int row = blockIdx.x;
    const float4* a  = (const float4*)(adj   + (size_t)row * NN);
    const float4* l  = (const float4*)(learn + (size_t)row * NN);
    const float4* nz = (const float4*)(noise + (size_t)row * NN);
    float acc = 0.f;
#pragma unroll
    for (int it = 0; it < NN / 4 / 256; ++it) {
        const int i = threadIdx.x + it * 256;
        const float4 av = a[i], lv = l[i], nv = nz[i];
        acc += (av.x + av.y + av.z + av.w)
             + (lv.x + lv.y + lv.z + lv.w)
             + EPSF * (nv.x + nv.y + nv.z + nv.w);
    }
#pragma unroll
    for (int off = 32; off; off >>= 1) acc += __shfl_down(acc, off);
    __shared__ float red[4];
    if ((threadIdx.x & 63) == 0) red[threadIdx.x >> 6] = acc;
    __syncthreads();
    if (threadIdx.x == 0) {
        const float d = red[0] + red[1] + red[2] + red[3] + 1.0f;  // + eye
        s_out[row] = rsqrtf(d + EPSF);
    }
}

// ---------------------------------------------------------------------------
// Pass 1b: SS[j][k] = s[j] * (x @ W)[j][k], stored transposed as bf16:
//          ss_t[k][j]  (128 x 8192, 2 MB -> L2 resident for pass 2)
// ---------------------------------------------------------------------------
__global__ __launch_bounds__(256) void support_kernel(
    const float* __restrict__ x, const float* __restrict__ w,
    const float* __restrict__ s, unsigned short* __restrict__ ss_t)
{
    __shared__ float Ws[128 * 128];    // 64 KB
    __shared__ float Xs[32][128];      // 16 KB
    for (int i = threadIdx.x; i < 128 * 128 / 4; i += 256)
        ((float4*)Ws)[i] = ((const float4*)w)[i];
    const int rbase = blockIdx.x * 32;
    for (int i = threadIdx.x; i < 32 * 128 / 4; i += 256)
        ((float4*)&Xs[0][0])[i] = ((const float4*)(x + (size_t)rbase * 128))[i];
    __syncthreads();

    const int c = threadIdx.x & 127;
    const int h = threadIdx.x >> 7;
    for (int r = h; r < 32; r += 2) {
        float acc = 0.f;
#pragma unroll 8
        for (int k = 0; k < 128; ++k) acc += Xs[r][k] * Ws[k * 128 + c];
        const int grow = rbase + r;
        ss_t[(size_t)c * NN + grow] = f2bf(acc * s[grow]);
    }
}

// ---------------------------------------------------------------------------
// Pass 2: out[i][n] = s[i] * ( sum_j L[i][j]*SS[j][n]  +  SS[i][n] )
// bf16 MFMA 16x16x32; A built in registers from 3 global streams (no LDS);
// B frags are contiguous 16B loads from transposed ss_t (L2-hit).
// Split-K x4 with f32 atomicAdd into zeroed out.
// ---------------------------------------------------------------------------
__global__ __launch_bounds__(256) void gcn_spmm_kernel(
    const float* __restrict__ adj, const float* __restrict__ learn,
    const float* __restrict__ noise, const unsigned short* __restrict__ ss_t,
    const float* __restrict__ s, float* __restrict__ out)
{
    const int rb   = blockIdx.x;        // 0..127: 64-row block
    const int ks   = blockIdx.y;        // 0..KSPLIT-1
    const int lane = threadIdx.x & 63;
    const int wave = threadIdx.x >> 6;
    const int m = lane & 15;            // A-row / B-col within fragment
    const int b = lane >> 4;            // k-subgroup (8 elems each)
    const int i0 = rb * 64 + wave * 16;
    const size_t rowoff = (size_t)(i0 + m) * NN;
    const int kbeg = ks * (NN / KSPLIT);
    const int kend = kbeg + (NN / KSPLIT);

    f32x4_t acc[8];
#pragma unroll
    for (int t = 0; t < 8; ++t) acc[t] = (f32x4_t){0.f, 0.f, 0.f, 0.f};

    for (int kk = kbeg; kk < kend; kk += 32) {
        const int col = kk + 8 * b;
        const float4 a0 = *(const float4*)(adj   + rowoff + col);
        const float4 a1 = *(const float4*)(adj   + rowoff + col + 4);
        const float4 l0 = *(const float4*)(learn + rowoff + col);
        const float4 l1 = *(const float4*)(learn + rowoff + col + 4);
        const float4 n0 = *(const float4*)(noise + rowoff + col);
        const float4 n1 = *(const float4*)(noise + rowoff + col + 4);
        short8_t afrag;
        afrag[0] = (short)f2bf(a0.x + l0.x + EPSF * n0.x);
        afrag[1] = (short)f2bf(a0.y + l0.y + EPSF * n0.y);
        afrag[2] = (short)f2bf(a0.z + l0.z + EPSF * n0.z);
        afrag[3] = (short)f2bf(a0.w + l0.w + EPSF * n0.w);
        afrag[4] = (short)f2bf(a1.x + l1.x + EPSF * n1.x);
        afrag[5] = (short)f2bf(a1.y + l1.y + EPSF * n1.y);
        afrag[6] = (short)f2bf(a1.z + l1.z + EPSF * n1.z);
        afrag[7] = (short)f2bf(a1.w + l1.w + EPSF * n1.w);
#pragma unroll
        for (int nt = 0; nt < 8; ++nt) {
            const short8_t bfrag =
                *(const short8_t*)(ss_t + (size_t)(nt * 16 + m) * NN + col);
            acc[nt] = __builtin_amdgcn_mfma_f32_16x16x32_bf16(afrag, bfrag,
                                                              acc[nt], 0, 0, 0);
        }
    }

    // C/D layout: col = lane&15, row = (lane>>4)*4 + reg  [measured m89/m91]
#pragma unroll
    for (int nt = 0; nt < 8; ++nt) {
        const int n = nt * 16 + m;
#pragma unroll
        for (int r = 0; r < 4; ++r) {
            const int ro = i0 + 4 * b + r;
            float v = acc[nt][r];
            if (ks == 0) v += bf2f(ss_t[(size_t)n * NN + ro]);  // + I * SS
            atomicAdd(out + (size_t)ro * FF + n, s[ro] * v);
        }
    }
}

extern "C" void kernel_launch(void* const* d_in, const int* in_sizes, int n_in,
                              void* d_out, int out_size, void* d_ws, size_t ws_size,
                              hipStream_t stream) {
    const float* x     = (const float*)d_in[0];
    const float* adj   = (const float*)d_in[1];
    const float* noise = (const float*)d_in[2];
    const float* w     = (const float*)d_in[3];
    const float* learn = (const float*)d_in[4];
    float* out = (float*)d_out;

    float* s = (float*)d_ws;                                        // 32 KB
    unsigned short* ss_t =
        (unsigned short*)((char*)d_ws + NN * sizeof(float));        // 2 MB

    hipMemsetAsync(d_out, 0, (size_t)NN * FF * sizeof(float), stream);
    degree_kernel<<<NN, 256, 0, stream>>>(adj, learn, noise, s);
    support_kernel<<<NN / 32, 256, 0, stream>>>(x, w, s, ss_t);
    gcn_spmm_kernel<<<dim3(NN / 64, KSPLIT), 256, 0, stream>>>(
        adj, learn, noise, ss_t, s, out);
}

// Round 2
// 341.207 us; speedup vs baseline: 1.2452x; 1.2452x over previous
//
#include <hip/hip_runtime.h>
#include <hip/hip_bf16.h>
#include <cstddef>

#define NN 8192
#define FF 128
#define EPSF 1e-8f
#define KSPLIT 4

typedef __attribute__((ext_vector_type(8))) short short8_t;
typedef __attribute__((ext_vector_type(4))) float f32x4_t;

static __device__ __forceinline__ unsigned short f2bf(float f) {
    unsigned u = __builtin_bit_cast(unsigned, f);
    u = (u + 0x7FFFu + ((u >> 16) & 1u)) >> 16;   // round-to-nearest-even
    return (unsigned short)u;
}
static __device__ __forceinline__ float bf2f(unsigned short h) {
    return __builtin_bit_cast(float, ((unsigned)h) << 16);
}

// ---------------------------------------------------------------------------
// Pass A (fused): L = adj + learn + eps*noise; write L as bf16 (128 MB);
// degree[i] = sum_j L[i][j] + 1;  s[i] = rsqrt(degree + eps).
// One block per row; 768 MB read + 128 MB write, pure streaming.
// ---------------------------------------------------------------------------
__global__ __launch_bounds__(256) void fuse_degree_kernel(
    const float* __restrict__ adj, const float* __restrict__ learn,
    const float* __restrict__ noise, unsigned short* __restrict__ Lb,
    float* __restrict__ s_out)
{
    const int row = blockIdx.x;
    const size_t off = (size_t)row * NN;
    float acc = 0.f;
#pragma unroll
    for (int it = 0; it < NN / 8 / 256; ++it) {
        const int e = (threadIdx.x + it * 256) * 8;
        const float4 a0 = *(const float4*)(adj   + off + e);
        const float4 a1 = *(const float4*)(adj   + off + e + 4);
        const float4 l0 = *(const float4*)(learn + off + e);
        const float4 l1 = *(const float4*)(learn + off + e + 4);
        const float4 n0 = *(const float4*)(noise + off + e);
        const float4 n1 = *(const float4*)(noise + off + e + 4);
        float v[8];
        v[0] = a0.x + l0.x + EPSF * n0.x;  v[1] = a0.y + l0.y + EPSF * n0.y;
        v[2] = a0.z + l0.z + EPSF * n0.z;  v[3] = a0.w + l0.w + EPSF * n0.w;
        v[4] = a1.x + l1.x + EPSF * n1.x;  v[5] = a1.y + l1.y + EPSF * n1.y;
        v[6] = a1.z + l1.z + EPSF * n1.z;  v[7] = a1.w + l1.w + EPSF * n1.w;
        short8_t pk;
#pragma unroll
        for (int j = 0; j < 8; ++j) { pk[j] = (short)f2bf(v[j]); acc += v[j]; }
        *(short8_t*)(Lb + off + e) = pk;
    }
#pragma unroll
    for (int o = 32; o; o >>= 1) acc += __shfl_down(acc, o);
    __shared__ float red[4];
    if ((threadIdx.x & 63) == 0) red[threadIdx.x >> 6] = acc;
    __syncthreads();
    if (threadIdx.x == 0) {
        const float d = red[0] + red[1] + red[2] + red[3] + 1.0f;  // + eye
        s_out[row] = rsqrtf(d + EPSF);
    }
}

// ---------------------------------------------------------------------------
// Pass B: SS[j][k] = s[j] * (x @ W)[j][k], stored transposed bf16:
//         ss_t[k][j]  (128 x 8192, 2 MB -> L2-resident for pass C)
// ---------------------------------------------------------------------------
__global__ __launch_bounds__(256) void support_kernel(
    const float* __restrict__ x, const float* __restrict__ w,
    const float* __restrict__ s, unsigned short* __restrict__ ss_t)
{
    __shared__ float Ws[128 * 128];    // 64 KB
    __shared__ float Xs[32][128];      // 16 KB
    for (int i = threadIdx.x; i < 128 * 128 / 4; i += 256)
        ((float4*)Ws)[i] = ((const float4*)w)[i];
    const int rbase = blockIdx.x * 32;
    for (int i = threadIdx.x; i < 32 * 128 / 4; i += 256)
        ((float4*)&Xs[0][0])[i] = ((const float4*)(x + (size_t)rbase * 128))[i];
    __syncthreads();

    const int c = threadIdx.x & 127;
    const int h = threadIdx.x >> 7;
    for (int r = h; r < 32; r += 2) {
        float acc = 0.f;
#pragma unroll 8
        for (int k = 0; k < 128; ++k) acc += Xs[r][k] * Ws[k * 128 + c];
        const int grow = rbase + r;
        ss_t[(size_t)c * NN + grow] = f2bf(acc * s[grow]);
    }
}

// ---------------------------------------------------------------------------
// Pass C: out[i][n] = s[i] * ( sum_j L[i][j]*SS[j][n] + SS[i][n] )
// A = bf16 L (128 MB, L3-warm); B = ss_t (L2). 512 blocks x 8 waves;
// in-block split-K x8, LDS partial reduce, no atomics.
// ---------------------------------------------------------------------------
#define PSTRIDE 132   // padded 128-col row stride (2-way bank alias only)
__global__ __launch_bounds__(512) void spmm_bf16_kernel(
    const unsigned short* __restrict__ Lb,
    const unsigned short* __restrict__ ss_t,
    const float* __restrict__ s, float* __restrict__ out)
{
    __shared__ float part[8][16 * PSTRIDE];   // 67.6 KB
    const int i0   = blockIdx.x * 16;
    const int wave = threadIdx.x >> 6;
    const int lane = threadIdx.x & 63;
    const int m = lane & 15;            // A-row / B-col within fragment
    const int b = lane >> 4;            // k-subgroup (8 elems each)
    const size_t arow = (size_t)(i0 + m) * NN;
    const int kbeg = wave * (NN / 8);

    f32x4_t acc[8];
#pragma unroll
    for (int t = 0; t < 8; ++t) acc[t] = (f32x4_t){0.f, 0.f, 0.f, 0.f};

    for (int kk = kbeg; kk < kbeg + NN / 8; kk += 32) {
        const int col = kk + 8 * b;
        const short8_t afrag = *(const short8_t*)(Lb + arow + col);
#pragma unroll
        for (int nt = 0; nt < 8; ++nt) {
            const short8_t bfrag =
                *(const short8_t*)(ss_t + (size_t)(nt * 16 + m) * NN + col);
            acc[nt] = __builtin_amdgcn_mfma_f32_16x16x32_bf16(afrag, bfrag,
                                                              acc[nt], 0, 0, 0);
        }
    }

    // C/D layout: col = lane&15, row = (lane>>4)*4 + reg  [measured m89/m91]
#pragma unroll
    for (int nt = 0; nt < 8; ++nt)
#pragma unroll
        for (int r = 0; r < 4; ++r)
            part[wave][(4 * b + r) * PSTRIDE + nt * 16 + m] = acc[nt][r];
    __syncthreads();

    for (int e = threadIdx.x; e < 16 * 128; e += 512) {
        const int rr = e >> 7, cc = e & 127;
        float v = 0.f;
#pragma unroll
        for (int w2 = 0; w2 < 8; ++w2) v += part[w2][rr * PSTRIDE + cc];
        const int gi = i0 + rr;
        v += bf2f(ss_t[(size_t)cc * NN + gi]);        // + I * SS
        out[(size_t)gi * FF + cc] = s[gi] * v;
    }
}

// ---------------------------------------------------------------------------
// Fallback path (R1, proven): used only if ws_size can't hold bf16 L.
// ---------------------------------------------------------------------------
__global__ __launch_bounds__(256) void degree_kernel(
    const float* __restrict__ adj, const float* __restrict__ learn,
    const float* __restrict__ noise, float* __restrict__ s_out)
{
    const int row = blockIdx.x;
    const float4* a  = (const float4*)(adj   + (size_t)row * NN);
    const float4* l  = (const float4*)(learn + (size_t)row * NN);
    const float4* nz = (const float4*)(noise + (size_t)row * NN);
    float acc = 0.f;
#pragma unroll
    for (int it = 0; it < NN / 4 / 256; ++it) {
        const int i = threadIdx.x + it * 256;
        const float4 av = a[i], lv = l[i], nv = nz[i];
        acc += (av.x + av.y + av.z + av.w)
             + (lv.x + lv.y + lv.z + lv.w)
             + EPSF * (nv.x + nv.y + nv.z + nv.w);
    }
#pragma unroll
    for (int off = 32; off; off >>= 1) acc += __shfl_down(acc, off);
    __shared__ float red[4];
    if ((threadIdx.x & 63) == 0) red[threadIdx.x >> 6] = acc;
    __syncthreads();
    if (threadIdx.x == 0) {
        const float d = red[0] + red[1] + red[2] + red[3] + 1.0f;
        s_out[row] = rsqrtf(d + EPSF);
    }
}

__global__ __launch_bounds__(256) void gcn_spmm_kernel(
    const float* __restrict__ adj, const float* __restrict__ learn,
    const float* __restrict__ noise, const unsigned short* __restrict__ ss_t,
    const float* __restrict__ s, float* __restrict__ out)
{
    const int rb   = blockIdx.x;
    const int ks   = blockIdx.y;
    const int lane = threadIdx.x & 63;
    const int wave = threadIdx.x >> 6;
    const int m = lane & 15;
    const int b = lane >> 4;
    const int i0 = rb * 64 + wave * 16;
    const size_t rowoff = (size_t)(i0 + m) * NN;
    const int kbeg = ks * (NN / KSPLIT);
    const int kend = kbeg + (NN / KSPLIT);

    f32x4_t acc[8];
#pragma unroll
    for (int t = 0; t < 8; ++t) acc[t] = (f32x4_t){0.f, 0.f, 0.f, 0.f};

    for (int kk = kbeg; kk < kend; kk += 32) {
        const int col = kk + 8 * b;
        const float4 a0 = *(const float4*)(adj   + rowoff + col);
        const float4 a1 = *(const float4*)(adj   + rowoff + col + 4);
        const float4 l0 = *(const float4*)(learn + rowoff + col);
        const float4 l1 = *(const float4*)(learn + rowoff + col + 4);
        const float4 n0 = *(const float4*)(noise + rowoff + col);
        const float4 n1 = *(const float4*)(noise + rowoff + col + 4);
        short8_t afrag;
        afrag[0] = (short)f2bf(a0.x + l0.x + EPSF * n0.x);
        afrag[1] = (short)f2bf(a0.y + l0.y + EPSF * n0.y);
        afrag[2] = (short)f2bf(a0.z + l0.z + EPSF * n0.z);
        afrag[3] = (short)f2bf(a0.w + l0.w + EPSF * n0.w);
        afrag[4] = (short)f2bf(a1.x + l1.x + EPSF * n1.x);
        afrag[5] = (short)f2bf(a1.y + l1.y + EPSF * n1.y);
        afrag[6] = (short)f2bf(a1.z + l1.z + EPSF * n1.z);
        afrag[7] = (short)f2bf(a1.w + l1.w + EPSF * n1.w);
#pragma unroll
        for (int nt = 0; nt < 8; ++nt) {
            const short8_t bfrag =
                *(const short8_t*)(ss_t + (size_t)(nt * 16 + m) * NN + col);
            acc[nt] = __builtin_amdgcn_mfma_f32_16x16x32_bf16(afrag, bfrag,
                                                              acc[nt], 0, 0, 0);
        }
    }
#pragma unroll
    for (int nt = 0; nt < 8; ++nt) {
        const int n = nt * 16 + m;
#pragma unroll
        for (int r = 0; r < 4; ++r) {
            const int ro = i0 + 4 * b + r;
            float v = acc[nt][r];
            if (ks == 0) v += bf2f(ss_t[(size_t)n * NN + ro]);
            atomicAdd(out + (size_t)ro * FF + n, s[ro] * v);
        }
    }
}

extern "C" void kernel_launch(void* const* d_in, const int* in_sizes, int n_in,
                              void* d_out, int out_size, void* d_ws, size_t ws_size,
                              hipStream_t stream) {
    const float* x     = (const float*)d_in[0];
    const float* adj   = (const float*)d_in[1];
    const float* noise = (const float*)d_in[2];
    const float* w     = (const float*)d_in[3];
    const float* learn = (const float*)d_in[4];
    float* out = (float*)d_out;

    float* s = (float*)d_ws;                                        // 32 KB
    unsigned short* ss_t =
        (unsigned short*)((char*)d_ws + NN * sizeof(float));        // 2 MB
    unsigned short* Lb =
        (unsigned short*)((char*)d_ws + NN * sizeof(float)
                          + (size_t)FF * NN * sizeof(unsigned short));

    const size_t need = NN * sizeof(float)
                      + (size_t)FF * NN * sizeof(unsigned short)
                      + (size_t)NN * NN * sizeof(unsigned short);   // ~130.3 MB

    if (ws_size >= need) {
        fuse_degree_kernel<<<NN, 256, 0, stream>>>(adj, learn, noise, Lb, s);
        support_kernel<<<NN / 32, 256, 0, stream>>>(x, w, s, ss_t);
        spmm_bf16_kernel<<<NN / 16, 512, 0, stream>>>(Lb, ss_t, s, out);
    } else {
        hipMemsetAsync(d_out, 0, (size_t)NN * FF * sizeof(float), stream);
        degree_kernel<<<NN, 256, 0, stream>>>(adj, learn, noise, s);
        support_kernel<<<NN / 32, 256, 0, stream>>>(x, w, s, ss_t);
        gcn_spmm_kernel<<<dim3(NN / 64, KSPLIT), 256, 0, stream>>>(
            adj, learn, noise, ss_t, s, out);
    }
}

// Round 3
// 288.749 us; speedup vs baseline: 1.4715x; 1.1817x over previous
//
#include <hip/hip_runtime.h>
#include <hip/hip_bf16.h>
#include <cstddef>

#define NN 8192
#define FF 128
#define EPSF 1e-8f
#define KSPLIT 4

typedef __attribute__((ext_vector_type(8))) short short8_t;
typedef __attribute__((ext_vector_type(4))) float f32x4_t;

static __device__ __forceinline__ unsigned short f2bf(float f) {
    unsigned u = __builtin_bit_cast(unsigned, f);
    u = (u + 0x7FFFu + ((u >> 16) & 1u)) >> 16;   // round-to-nearest-even
    return (unsigned short)u;
}
static __device__ __forceinline__ float bf2f(unsigned short h) {
    return __builtin_bit_cast(float, ((unsigned)h) << 16);
}

// ---------------------------------------------------------------------------
// Pass A (fused): L = adj + learn  [the eps*noise term is <=1e-8, which is
// far below bf16 ulp of L (~4e-3) and contributes ~5e-9 relative to the
// degree -> provably invisible at the 9.7e-4 threshold; we skip reading the
// 256 MB noise matrix entirely].
// Write L as bf16 (128 MB); degree[i] = sum_j L[i][j] + 1;
// s[i] = rsqrt(degree + eps).  512 MB read + 128 MB write, pure streaming.
// ---------------------------------------------------------------------------
__global__ __launch_bounds__(256) void fuse_degree_kernel(
    const float* __restrict__ adj, const float* __restrict__ learn,
    unsigned short* __restrict__ Lb, float* __restrict__ s_out)
{
    const int row = blockIdx.x;
    const size_t off = (size_t)row * NN;
    float acc = 0.f;
#pragma unroll
    for (int it = 0; it < NN / 8 / 256; ++it) {
        const int e = (threadIdx.x + it * 256) * 8;
        const float4 a0 = *(const float4*)(adj   + off + e);
        const float4 a1 = *(const float4*)(adj   + off + e + 4);
        const float4 l0 = *(const float4*)(learn + off + e);
        const float4 l1 = *(const float4*)(learn + off + e + 4);
        float v[8];
        v[0] = a0.x + l0.x;  v[1] = a0.y + l0.y;
        v[2] = a0.z + l0.z;  v[3] = a0.w + l0.w;
        v[4] = a1.x + l1.x;  v[5] = a1.y + l1.y;
        v[6] = a1.z + l1.z;  v[7] = a1.w + l1.w;
        short8_t pk;
#pragma unroll
        for (int j = 0; j < 8; ++j) { pk[j] = (short)f2bf(v[j]); acc += v[j]; }
        *(short8_t*)(Lb + off + e) = pk;
    }
#pragma unroll
    for (int o = 32; o; o >>= 1) acc += __shfl_down(acc, o);
    __shared__ float red[4];
    if ((threadIdx.x & 63) == 0) red[threadIdx.x >> 6] = acc;
    __syncthreads();
    if (threadIdx.x == 0) {
        const float d = red[0] + red[1] + red[2] + red[3] + 1.0f;  // + eye
        s_out[row] = rsqrtf(d + EPSF);
    }
}

// ---------------------------------------------------------------------------
// Pass B: SS[j][k] = s[j] * (x @ W)[j][k], stored transposed bf16:
//         ss_t[k][j]  (128 x 8192, 2 MB -> L2-resident for pass C)
// ---------------------------------------------------------------------------
__global__ __launch_bounds__(256) void support_kernel(
    const float* __restrict__ x, const float* __restrict__ w,
    const float* __restrict__ s, unsigned short* __restrict__ ss_t)
{
    __shared__ float Ws[128 * 128];    // 64 KB
    __shared__ float Xs[32][128];      // 16 KB
    for (int i = threadIdx.x; i < 128 * 128 / 4; i += 256)
        ((float4*)Ws)[i] = ((const float4*)w)[i];
    const int rbase = blockIdx.x * 32;
    for (int i = threadIdx.x; i < 32 * 128 / 4; i += 256)
        ((float4*)&Xs[0][0])[i] = ((const float4*)(x + (size_t)rbase * 128))[i];
    __syncthreads();

    const int c = threadIdx.x & 127;
    const int h = threadIdx.x >> 7;
    for (int r = h; r < 32; r += 2) {
        float acc = 0.f;
#pragma unroll 8
        for (int k = 0; k < 128; ++k) acc += Xs[r][k] * Ws[k * 128 + c];
        const int grow = rbase + r;
        ss_t[(size_t)c * NN + grow] = f2bf(acc * s[grow]);
    }
}

// ---------------------------------------------------------------------------
// Pass C: out[i][n] = s[i] * ( sum_j L[i][j]*SS[j][n] + SS[i][n] )
// A = bf16 L (128 MB, L3-warm); B = ss_t (L2). 512 blocks x 8 waves;
// in-block split-K x8, LDS partial reduce, no atomics.
// ---------------------------------------------------------------------------
#define PSTRIDE 132   // padded 128-col row stride (2-way bank alias only)
__global__ __launch_bounds__(512) void spmm_bf16_kernel(
    const unsigned short* __restrict__ Lb,
    const unsigned short* __restrict__ ss_t,
    const float* __restrict__ s, float* __restrict__ out)
{
    __shared__ float part[8][16 * PSTRIDE];   // 67.6 KB
    const int i0   = blockIdx.x * 16;
    const int wave = threadIdx.x >> 6;
    const int lane = threadIdx.x & 63;
    const int m = lane & 15;            // A-row / B-col within fragment
    const int b = lane >> 4;            // k-subgroup (8 elems each)
    const size_t arow = (size_t)(i0 + m) * NN;
    const int kbeg = wave * (NN / 8);

    f32x4_t acc[8];
#pragma unroll
    for (int t = 0; t < 8; ++t) acc[t] = (f32x4_t){0.f, 0.f, 0.f, 0.f};

    for (int kk = kbeg; kk < kbeg + NN / 8; kk += 32) {
        const int col = kk + 8 * b;
        const short8_t afrag = *(const short8_t*)(Lb + arow + col);
#pragma unroll
        for (int nt = 0; nt < 8; ++nt) {
            const short8_t bfrag =
                *(const short8_t*)(ss_t + (size_t)(nt * 16 + m) * NN + col);
            acc[nt] = __builtin_amdgcn_mfma_f32_16x16x32_bf16(afrag, bfrag,
                                                              acc[nt], 0, 0, 0);
        }
    }

    // C/D layout: col = lane&15, row = (lane>>4)*4 + reg  [measured m89/m91]
#pragma unroll
    for (int nt = 0; nt < 8; ++nt)
#pragma unroll
        for (int r = 0; r < 4; ++r)
            part[wave][(4 * b + r) * PSTRIDE + nt * 16 + m] = acc[nt][r];
    __syncthreads();

    for (int e = threadIdx.x; e < 16 * 128; e += 512) {
        const int rr = e >> 7, cc = e & 127;
        float v = 0.f;
#pragma unroll
        for (int w2 = 0; w2 < 8; ++w2) v += part[w2][rr * PSTRIDE + cc];
        const int gi = i0 + rr;
        v += bf2f(ss_t[(size_t)cc * NN + gi]);        // + I * SS
        out[(size_t)gi * FF + cc] = s[gi] * v;
    }
}

// ---------------------------------------------------------------------------
// Fallback path (R1, proven): used only if ws_size can't hold bf16 L.
// ---------------------------------------------------------------------------
__global__ __launch_bounds__(256) void degree_kernel(
    const float* __restrict__ adj, const float* __restrict__ learn,
    const float* __restrict__ noise, float* __restrict__ s_out)
{
    const int row = blockIdx.x;
    const float4* a  = (const float4*)(adj   + (size_t)row * NN);
    const float4* l  = (const float4*)(learn + (size_t)row * NN);
    const float4* nz = (const float4*)(noise + (size_t)row * NN);
    float acc = 0.f;
#pragma unroll
    for (int it = 0; it < NN / 4 / 256; ++it) {
        const int i = threadIdx.x + it * 256;
        const float4 av = a[i], lv = l[i], nv = nz[i];
        acc += (av.x + av.y + av.z + av.w)
             + (lv.x + lv.y + lv.z + lv.w)
             + EPSF * (nv.x + nv.y + nv.z + nv.w);
    }
#pragma unroll
    for (int off = 32; off; off >>= 1) acc += __shfl_down(acc, off);
    __shared__ float red[4];
    if ((threadIdx.x & 63) == 0) red[threadIdx.x >> 6] = acc;
    __syncthreads();
    if (threadIdx.x == 0) {
        const float d = red[0] + red[1] + red[2] + red[3] + 1.0f;
        s_out[row] = rsqrtf(d + EPSF);
    }
}

__global__ __launch_bounds__(256) void gcn_spmm_kernel(
    const float* __restrict__ adj, const float* __restrict__ learn,
    const float* __restrict__ noise, const unsigned short* __restrict__ ss_t,
    const float* __restrict__ s, float* __restrict__ out)
{
    const int rb   = blockIdx.x;
    const int ks   = blockIdx.y;
    const int lane = threadIdx.x & 63;
    const int wave = threadIdx.x >> 6;
    const int m = lane & 15;
    const int b = lane >> 4;
    const int i0 = rb * 64 + wave * 16;
    const size_t rowoff = (size_t)(i0 + m) * NN;
    const int kbeg = ks * (NN / KSPLIT);
    const int kend = kbeg + (NN / KSPLIT);

    f32x4_t acc[8];
#pragma unroll
    for (int t = 0; t < 8; ++t) acc[t] = (f32x4_t){0.f, 0.f, 0.f, 0.f};

    for (int kk = kbeg; kk < kend; kk += 32) {
        const int col = kk + 8 * b;
        const float4 a0 = *(const float4*)(adj   + rowoff + col);
        const float4 a1 = *(const float4*)(adj   + rowoff + col + 4);
        const float4 l0 = *(const float4*)(learn + rowoff + col);
        const float4 l1 = *(const float4*)(learn + rowoff + col + 4);
        const float4 n0 = *(const float4*)(noise + rowoff + col);
        const float4 n1 = *(const float4*)(noise + rowoff + col + 4);
        short8_t afrag;
        afrag[0] = (short)f2bf(a0.x + l0.x + EPSF * n0.x);
        afrag[1] = (short)f2bf(a0.y + l0.y + EPSF * n0.y);
        afrag[2] = (short)f2bf(a0.z + l0.z + EPSF * n0.z);
        afrag[3] = (short)f2bf(a0.w + l0.w + EPSF * n0.w);
        afrag[4] = (short)f2bf(a1.x + l1.x + EPSF * n1.x);
        afrag[5] = (short)f2bf(a1.y + l1.y + EPSF * n1.y);
        afrag[6] = (short)f2bf(a1.z + l1.z + EPSF * n1.z);
        afrag[7] = (short)f2bf(a1.w + l1.w + EPSF * n1.w);
#pragma unroll
        for (int nt = 0; nt < 8; ++nt) {
            const short8_t bfrag =
                *(const short8_t*)(ss_t + (size_t)(nt * 16 + m) * NN + col);
            acc[nt] = __builtin_amdgcn_mfma_f32_16x16x32_bf16(afrag, bfrag,
                                                              acc[nt], 0, 0, 0);
        }
    }
#pragma unroll
    for (int nt = 0; nt < 8; ++nt) {
        const int n = nt * 16 + m;
#pragma unroll
        for (int r = 0; r < 4; ++r) {
            const int ro = i0 + 4 * b + r;
            float v = acc[nt][r];
            if (ks == 0) v += bf2f(ss_t[(size_t)n * NN + ro]);
            atomicAdd(out + (size_t)ro * FF + n, s[ro] * v);
        }
    }
}

extern "C" void kernel_launch(void* const* d_in, const int* in_sizes, int n_in,
                              void* d_out, int out_size, void* d_ws, size_t ws_size,
                              hipStream_t stream) {
    const float* x     = (const float*)d_in[0];
    const float* adj   = (const float*)d_in[1];
    const float* noise = (const float*)d_in[2];
    const float* w     = (const float*)d_in[3];
    const float* learn = (const float*)d_in[4];
    float* out = (float*)d_out;

    float* s = (float*)d_ws;                                        // 32 KB
    unsigned short* ss_t =
        (unsigned short*)((char*)d_ws + NN * sizeof(float));        // 2 MB
    unsigned short* Lb =
        (unsigned short*)((char*)d_ws + NN * sizeof(float)
                          + (size_t)FF * NN * sizeof(unsigned short));

    const size_t need = NN * sizeof(float)
                      + (size_t)FF * NN * sizeof(unsigned short)
                      + (size_t)NN * NN * sizeof(unsigned short);   // ~130.3 MB

    if (ws_size >= need) {
        fuse_degree_kernel<<<NN, 256, 0, stream>>>(adj, learn, Lb, s);
        support_kernel<<<NN / 32, 256, 0, stream>>>(x, w, s, ss_t);
        spmm_bf16_kernel<<<NN / 16, 512, 0, stream>>>(Lb, ss_t, s, out);
    } else {
        hipMemsetAsync(d_out, 0, (size_t)NN * FF * sizeof(float), stream);
        degree_kernel<<<NN, 256, 0, stream>>>(adj, learn, noise, s);
        support_kernel<<<NN / 32, 256, 0, stream>>>(x, w, s, ss_t);
        gcn_spmm_kernel<<<dim3(NN / 64, KSPLIT), 256, 0, stream>>>(
            adj, learn, noise, ss_t, s, out);
    }
}

// Round 4
// 267.865 us; speedup vs baseline: 1.5862x; 1.0780x over previous
//
#include <hip/hip_runtime.h>
#include <hip/hip_bf16.h>
#include <cstddef>

#define NN 8192
#define FF 128
#define EPSF 1e-8f
#define KSPLIT 8   // grid-level split-K for spmm

typedef __attribute__((ext_vector_type(8))) short short8_t;
typedef __attribute__((ext_vector_type(4))) float f32x4_t;
typedef __attribute__((ext_vector_type(4))) unsigned short us4_t;

static __device__ __forceinline__ unsigned short f2bf(float f) {
    unsigned u = __builtin_bit_cast(unsigned, f);
    u = (u + 0x7FFFu + ((u >> 16) & 1u)) >> 16;   // round-to-nearest-even
    return (unsigned short)u;
}
static __device__ __forceinline__ float bf2f(unsigned short h) {
    return __builtin_bit_cast(float, ((unsigned)h) << 16);
}

// ---------------------------------------------------------------------------
// Pass A: L = adj + learn (eps*noise <= 1e-8 is below bf16 ulp of L and
// ~5e-9 relative on the degree -> noise stream skipped, proven R3).
// Write L as bf16 (128 MB); s[i] = rsqrt(rowsum + 1 + eps).
// MLP fix: ALL 16 float4 loads issued up-front (R3 ran at VGPR=32 ->
// ~2 loads in flight -> 3.9 TB/s latency-limited).
// ---------------------------------------------------------------------------
__global__ __launch_bounds__(256) void fuse_degree_kernel(
    const float* __restrict__ adj, const float* __restrict__ learn,
    unsigned short* __restrict__ Lb, float* __restrict__ s_out)
{
    const int row = blockIdx.x;
    const size_t off = (size_t)row * NN;
    const f32x4_t* ap = (const f32x4_t*)(adj   + off);
    const f32x4_t* lp = (const f32x4_t*)(learn + off);
    us4_t* op = (us4_t*)(Lb + off);

    f32x4_t a[8], l[8];
#pragma unroll
    for (int j = 0; j < 8; ++j) a[j] = ap[threadIdx.x + j * 256];
#pragma unroll
    for (int j = 0; j < 8; ++j) l[j] = lp[threadIdx.x + j * 256];

    float acc = 0.f;
#pragma unroll
    for (int j = 0; j < 8; ++j) {
        const f32x4_t v = a[j] + l[j];
        us4_t pk;
        pk.x = f2bf(v.x); pk.y = f2bf(v.y);
        pk.z = f2bf(v.z); pk.w = f2bf(v.w);
        op[threadIdx.x + j * 256] = pk;
        acc += (v.x + v.y) + (v.z + v.w);
    }

#pragma unroll
    for (int o = 32; o; o >>= 1) acc += __shfl_down(acc, o);
    __shared__ float red[4];
    if ((threadIdx.x & 63) == 0) red[threadIdx.x >> 6] = acc;
    __syncthreads();
    if (threadIdx.x == 0) {
        const float d = red[0] + red[1] + red[2] + red[3] + 1.0f;  // + eye
        s_out[row] = rsqrtf(d + EPSF);
    }
}

// ---------------------------------------------------------------------------
// Pass B: ss_t[n][j] = s[j] * (x @ W)[j][n]  (bf16, 2 MB, L2/L3-resident)
// ---------------------------------------------------------------------------
__global__ __launch_bounds__(256) void support_kernel(
    const float* __restrict__ x, const float* __restrict__ w,
    const float* __restrict__ s, unsigned short* __restrict__ ss_t)
{
    __shared__ float Ws[128 * 128];    // 64 KB
    __shared__ float Xs[32][128];      // 16 KB
    for (int i = threadIdx.x; i < 128 * 128 / 4; i += 256)
        ((float4*)Ws)[i] = ((const float4*)w)[i];
    const int rbase = blockIdx.x * 32;
    for (int i = threadIdx.x; i < 32 * 128 / 4; i += 256)
        ((float4*)&Xs[0][0])[i] = ((const float4*)(x + (size_t)rbase * 128))[i];
    __syncthreads();

    const int c = threadIdx.x & 127;
    const int h = threadIdx.x >> 7;
    for (int r = h; r < 32; r += 2) {
        float acc = 0.f;
#pragma unroll 8
        for (int k = 0; k < 128; ++k) acc += Xs[r][k] * Ws[k * 128 + c];
        const int grow = rbase + r;
        ss_t[(size_t)c * NN + grow] = f2bf(acc * s[grow]);
    }
}

// ---------------------------------------------------------------------------
// Pass C: out[i][n] = s[i] * ( sum_j L[i][j]*SS[j][n] + SS[i][n] )
// Register-blocked: wave owns 32 rows (2 A-frags per B-frag), block = 128
// rows x 4 waves, KSPLIT=8 -> grid 512. B loads identical across the 4
// waves (L1 broadcast); B L2 traffic 1 GB -> 128 MB vs R3.
// ATOMIC=false: write split-K partials to ws (reduced by reduce_kernel).
// ATOMIC=true : proven R1-style atomicAdd epilogue (smaller-ws fallback).
// ---------------------------------------------------------------------------
template<bool ATOMIC>
__global__ __launch_bounds__(256) void spmm_bf16_kernel(
    const unsigned short* __restrict__ Lb,
    const unsigned short* __restrict__ ss_t,
    const float* __restrict__ s, float* __restrict__ outp)
{
    const int ks   = blockIdx.y;            // 0..KSPLIT-1
    const int i0   = blockIdx.x * 128;      // M-block base
    const int wave = threadIdx.x >> 6;      // 0..3
    const int lane = threadIdx.x & 63;
    const int m = lane & 15;                // A-row / B-col within fragment
    const int b = lane >> 4;                // k-subgroup (8 elems each)
    const size_t a0off = (size_t)(i0 + wave * 32 + m) * NN;
    const size_t a1off = a0off + (size_t)16 * NN;
    const int kbeg = ks * (NN / KSPLIT);

    f32x4_t acc[2][8];
#pragma unroll
    for (int f = 0; f < 2; ++f)
#pragma unroll
        for (int t = 0; t < 8; ++t) acc[f][t] = (f32x4_t){0.f, 0.f, 0.f, 0.f};

    for (int kk = kbeg; kk < kbeg + NN / KSPLIT; kk += 32) {
        const int col = kk + 8 * b;
        const short8_t af0 = *(const short8_t*)(Lb + a0off + col);
        const short8_t af1 = *(const short8_t*)(Lb + a1off + col);
#pragma unroll
        for (int nt = 0; nt < 8; ++nt) {
            const short8_t bf =
                *(const short8_t*)(ss_t + (size_t)(nt * 16 + m) * NN + col);
            acc[0][nt] = __builtin_amdgcn_mfma_f32_16x16x32_bf16(af0, bf,
                                                                 acc[0][nt], 0, 0, 0);
            acc[1][nt] = __builtin_amdgcn_mfma_f32_16x16x32_bf16(af1, bf,
                                                                 acc[1][nt], 0, 0, 0);
        }
    }

    // C/D layout: col = lane&15, row = (lane>>4)*4 + reg  [measured m89/m91]
#pragma unroll
    for (int f = 0; f < 2; ++f) {
#pragma unroll
        for (int nt = 0; nt < 8; ++nt) {
            const int n = nt * 16 + m;
#pragma unroll
            for (int r = 0; r < 4; ++r) {
                const int ro = i0 + wave * 32 + f * 16 + 4 * b + r;
                float v = acc[f][nt][r];
                if (ATOMIC) {
                    if (ks == 0) v += bf2f(ss_t[(size_t)n * NN + ro]);
                    atomicAdd(outp + (size_t)ro * FF + n, s[ro] * v);
                } else {
                    outp[(size_t)ks * NN * FF + (size_t)ro * FF + n] = v;
                }
            }
        }
    }
}

// Reduce KSPLIT partials + identity term + row scaling -> out (f32).
__global__ __launch_bounds__(256) void reduce_kernel(
    const float* __restrict__ part, const unsigned short* __restrict__ ss_t,
    const float* __restrict__ s, float* __restrict__ out)
{
    const int idx = blockIdx.x * 256 + threadIdx.x;   // 0 .. NN*FF-1
    const int gi = idx >> 7;          // row i
    const int cc = idx & 127;         // col n
    float v = 0.f;
#pragma unroll
    for (int k = 0; k < KSPLIT; ++k) v += part[(size_t)k * NN * FF + idx];
    v += bf2f(ss_t[(size_t)cc * NN + gi]);            // + I * SS
    out[idx] = s[gi] * v;
}

extern "C" void kernel_launch(void* const* d_in, const int* in_sizes, int n_in,
                              void* d_out, int out_size, void* d_ws, size_t ws_size,
                              hipStream_t stream) {
    const float* x     = (const float*)d_in[0];
    const float* adj   = (const float*)d_in[1];
    const float* w     = (const float*)d_in[3];
    const float* learn = (const float*)d_in[4];
    float* out = (float*)d_out;

    // ws layout: s | ss_t | Lb | (part)
    float* s = (float*)d_ws;
    unsigned short* ss_t = (unsigned short*)((char*)d_ws + NN * sizeof(float));
    unsigned short* Lb   = (unsigned short*)((char*)ss_t + (size_t)FF * NN * 2);
    float* part          = (float*)((char*)Lb + (size_t)NN * NN * 2);

    const size_t need_base = NN * 4 + (size_t)FF * NN * 2 + (size_t)NN * NN * 2;
    const size_t need_part = need_base + (size_t)KSPLIT * NN * FF * 4;  // ~162 MB

    fuse_degree_kernel<<<NN, 256, 0, stream>>>(adj, learn, Lb, s);
    support_kernel<<<NN / 32, 256, 0, stream>>>(x, w, s, ss_t);

    if (ws_size >= need_part) {
        spmm_bf16_kernel<false><<<dim3(NN / 128, KSPLIT), 256, 0, stream>>>(
            Lb, ss_t, s, part);
        reduce_kernel<<<NN * FF / 256, 256, 0, stream>>>(part, ss_t, s, out);
    } else {
        hipMemsetAsync(d_out, 0, (size_t)NN * FF * sizeof(float), stream);
        spmm_bf16_kernel<true><<<dim3(NN / 128, KSPLIT), 256, 0, stream>>>(
            Lb, ss_t, s, out);
    }
}